// Round 2
// baseline (1561.208 us; speedup 1.0000x reference)
//
#include <hip/hip_runtime.h>
#include <hip/hip_bf16.h>

typedef __hip_bfloat16 bf16;
typedef __attribute__((ext_vector_type(8))) short bf16x8;
typedef __attribute__((ext_vector_type(4))) float f32x4;

#define BIG_NEG -1000000000.0f

static constexpr int B_  = 256;
static constexpr int SX_ = 34;
static constexpr int SY_ = 34;
static constexpr int IND = 66;   // IN_DIM
static constexpr int OP_ = 80;   // padded OUT_DIM (65 -> 80)

__device__ __forceinline__ f32x4 mfma16(bf16x8 a, bf16x8 b, f32x4 c) {
  return __builtin_amdgcn_mfma_f32_16x16x32_bf16(a, b, c, 0, 0, 0);
}
__device__ __forceinline__ bf16x8 ldfrag(const bf16* p) {
  return *reinterpret_cast<const bf16x8*>(p);
}
__device__ __forceinline__ float sigm(float x)  { return 1.0f / (1.0f + __expf(-x)); }
__device__ __forceinline__ float tanhx(float x) { return 2.0f * sigm(2.0f * x) - 1.0f; }

// ---------------------------------------------------------------------------
// prep kernels
// ---------------------------------------------------------------------------
__global__ void decode_tokens(const float* __restrict__ src,
                              const float* __restrict__ tgt,
                              int* __restrict__ tok_x, int* __restrict__ tok_y) {
  int idx = blockIdx.x * 256 + threadIdx.x;
  const int half = SX_ * B_;
  if (idx >= 2 * half) return;
  const float* base = (idx < half) ? src : tgt;
  int* outp         = (idx < half) ? tok_x : tok_y;
  int k = (idx < half) ? idx : idx - half;
  const float* p = base + (size_t)k * IND;
  int tok = -1;
  for (int v = 0; v < IND; ++v) if (p[v] > 0.5f) tok = v;
  outp[k] = tok;
}

__global__ void pad_head_w(const float* __restrict__ Wsub, const float* __restrict__ Wins,
                           bf16* __restrict__ outs, bf16* __restrict__ outi) {
  int idx = blockIdx.x * 256 + threadIdx.x;  // over 80*1024
  if (idx >= OP_ * 1024) return;
  int r = idx >> 10;
  int c = idx & 1023;
  float vs = (r < 65) ? Wsub[r * 1024 + c] : 0.0f;
  float vi = (r < 65) ? Wins[r * 1024 + c] : 0.0f;
  outs[idx] = __float2bfloat16(vs);
  outi[idx] = __float2bfloat16(vi);
}

// ---------------------------------------------------------------------------
// persistent LSTM kernel: 256 blocks x 256 thr, one block per CU.
//   blocks [0,64)   : fwd LSTM  (H=512),  block owns 8 hidden x 4 gates
//   blocks [64,128) : rev LSTM  (H=512)
//   blocks [128,256): modern    (H=1024), block owns 8 hidden x 4 gates
// Weight slice (32 W-rows x K) staged once in LDS (bf16, chunk-XOR swizzle).
// c-state lives in registers for all 34 steps. Steps separated by a
// device-scope spin barrier (timeout-guarded: deadlock -> wrong answer,
// not a hang).
// ---------------------------------------------------------------------------
__device__ __forceinline__ void grid_barrier(unsigned* bar, unsigned target) {
  __syncthreads();
  if (threadIdx.x == 0) {
    __threadfence();                     // release: h stores visible device-wide
    atomicAdd(bar, 1u);
    long long t0 = __builtin_amdgcn_s_memrealtime();
    while (__hip_atomic_load(bar, __ATOMIC_RELAXED, __HIP_MEMORY_SCOPE_AGENT) < target) {
      __builtin_amdgcn_s_sleep(8);
      if (__builtin_amdgcn_s_memrealtime() - t0 > 10000000LL) break;  // ~100ms safety
    }
    __threadfence();                     // acquire
  }
  __syncthreads();
}

template <int HH>
__device__ __forceinline__ void step_body(
    int t, int tpos, const int* __restrict__ tok,
    const bf16* __restrict__ wslice,
    bf16* __restrict__ hall, int h0, float (&creg)[4][2],
    float bi, float bff, float bg, float bo,
    const float* __restrict__ wr_i, const float* __restrict__ wr_f,
    const float* __restrict__ wr_g, const float* __restrict__ wr_o) {
  const int lane = threadIdx.x & 63, wave = threadIdx.x >> 6;
  const int lo = lane & 15, q = lane >> 4, sw = lo & 7;
  const bf16* hsrc = hall + (size_t)t * B_ * HH;
  bf16* hdst = hall + (size_t)(t + 1) * B_ * HH;

  f32x4 acc[4][2];
#pragma unroll
  for (int mt = 0; mt < 4; ++mt) {
    acc[mt][0] = (f32x4){0.f, 0.f, 0.f, 0.f};
    acc[mt][1] = (f32x4){0.f, 0.f, 0.f, 0.f};
  }

  const bf16* ap[4];
#pragma unroll
  for (int mt = 0; mt < 4; ++mt)
    ap[mt] = hsrc + (size_t)(wave * 64 + mt * 16 + lo) * HH + q * 8;
  const bf16* wb0 = wslice + lo * HH;          // n-tile 0: rows (i,f) x h0..7
  const bf16* wb1 = wslice + (16 + lo) * HH;   // n-tile 1: rows (g,o) x h0..7

#pragma unroll 4
  for (int kk = 0; kk < HH; kk += 32) {
    int off = ((((kk >> 3) | q) ^ sw) << 3);   // chunk-XOR deswizzle
    bf16x8 b0 = *(const bf16x8*)(wb0 + off);
    bf16x8 b1 = *(const bf16x8*)(wb1 + off);
#pragma unroll
    for (int mt = 0; mt < 4; ++mt) {
      bf16x8 a = ldfrag(ap[mt] + kk);
      acc[mt][0] = mfma16(a, b0, acc[mt][0]);
      acc[mt][1] = mfma16(a, b1, acc[mt][1]);
    }
  }

  const int hh = sw;
  const bool hi = (lo >= 8);
  const int* tokp = tok + tpos * B_;
#pragma unroll
  for (int mt = 0; mt < 4; ++mt) {
    f32x4 t0 = acc[mt][0], t1 = acc[mt][1];
    f32x4 p0, p1;
#pragma unroll
    for (int c2 = 0; c2 < 4; ++c2) {
      p0[c2] = __shfl_xor(t0[c2], 8, 64);
      p1[c2] = __shfl_xor(t1[c2], 8, 64);
    }
#pragma unroll
    for (int rr = 0; rr < 2; ++rr) {
      int r = (hi ? 2 : 0) + rr;
      float iv = hi ? p0[r] : t0[r];
      float fv = hi ? t0[r] : p0[r];
      float gv = hi ? p1[r] : t1[r];
      float ov = hi ? t1[r] : p1[r];
      int b = wave * 64 + mt * 16 + q * 4 + r;
      int tk = tokp[b];
      if (tk >= 0) {
        iv += wr_i[tk]; fv += wr_f[tk]; gv += wr_g[tk]; ov += wr_o[tk];
      }
      iv += bi; fv += bff; gv += bg; ov += bo;
      float cold = creg[mt][rr];
      float cn = sigm(fv) * cold + sigm(iv) * tanhx(gv);
      float hn = sigm(ov) * tanhx(cn);
      creg[mt][rr] = cn;
      hdst[(size_t)b * HH + h0 + hh] = __float2bfloat16(hn);
    }
  }
}

__global__ __launch_bounds__(256) void lstm_persist(
    const int* __restrict__ tok_x, const int* __restrict__ tok_y,
    const float* __restrict__ Wih_f, const float* __restrict__ bf_v, const float* __restrict__ Whh_f,
    const float* __restrict__ Wih_r, const float* __restrict__ br_v, const float* __restrict__ Whh_r,
    const float* __restrict__ Wih_m, const float* __restrict__ bm_v, const float* __restrict__ Whh_m,
    bf16* __restrict__ fwd_all, bf16* __restrict__ rev_all, bf16* __restrict__ y_all,
    unsigned* __restrict__ bar) {
  __shared__ bf16 wslice[32 * 1024];   // 64 KB max (fwd/rev use 32 KB)

  const int blk = blockIdx.x;
  const int role = blk < 64 ? 0 : (blk < 128 ? 1 : 2);
  const int HH = (role == 2) ? 1024 : 512;
  const int h0 = (role == 0 ? blk : role == 1 ? blk - 64 : blk - 128) * 8;
  const float* Wih  = role == 0 ? Wih_f : role == 1 ? Wih_r : Wih_m;
  const float* bias = role == 0 ? bf_v  : role == 1 ? br_v  : bm_v;
  const float* Whh  = role == 0 ? Whh_f : role == 1 ? Whh_r : Whh_m;
  const int*  tok   = (role == 2) ? tok_y : tok_x;
  bf16* hall = role == 0 ? fwd_all : role == 1 ? rev_all : y_all;

  // ---- stage weight slice into LDS (f32 -> bf16, chunk-XOR swizzle) ----
  {
    const int shift = (HH == 1024) ? 7 : 6;
    const int K8 = HH >> 3;
    for (int ch = threadIdx.x; ch < 32 * K8; ch += 256) {
      int row = ch >> shift;
      int cc = ch & (K8 - 1);
      int gate = row >> 3, hh2 = row & 7;
      const float* gp = Whh + (size_t)(gate * HH + h0 + hh2) * HH + (cc << 3);
      float4 f0 = *(const float4*)gp;
      float4 f1 = *(const float4*)(gp + 4);
      bf16 tmp[8];
      tmp[0] = __float2bfloat16(f0.x); tmp[1] = __float2bfloat16(f0.y);
      tmp[2] = __float2bfloat16(f0.z); tmp[3] = __float2bfloat16(f0.w);
      tmp[4] = __float2bfloat16(f1.x); tmp[5] = __float2bfloat16(f1.y);
      tmp[6] = __float2bfloat16(f1.z); tmp[7] = __float2bfloat16(f1.w);
      *(bf16x8*)&wslice[row * HH + ((cc ^ hh2) << 3)] = *(bf16x8*)tmp;
    }
  }
  __syncthreads();

  const int lane = threadIdx.x & 63;
  const int lo = lane & 15;
  const int hh = lo & 7;
  const float* wr_i = Wih + (size_t)(0 * HH + h0 + hh) * IND;
  const float* wr_f = Wih + (size_t)(1 * HH + h0 + hh) * IND;
  const float* wr_g = Wih + (size_t)(2 * HH + h0 + hh) * IND;
  const float* wr_o = Wih + (size_t)(3 * HH + h0 + hh) * IND;
  const float bi  = bias[0 * HH + h0 + hh];
  const float bff = bias[1 * HH + h0 + hh];
  const float bg  = bias[2 * HH + h0 + hh];
  const float bo  = bias[3 * HH + h0 + hh];

  float creg[4][2] = {{0.f, 0.f}, {0.f, 0.f}, {0.f, 0.f}, {0.f, 0.f}};

  for (int t = 0; t < 34; ++t) {
    int tpos = (role == 1) ? (33 - t) : t;
    if (role == 2)
      step_body<1024>(t, tpos, tok, wslice, hall, h0, creg, bi, bff, bg, bo,
                      wr_i, wr_f, wr_g, wr_o);
    else
      step_body<512>(t, tpos, tok, wslice, hall, h0, creg, bi, bff, bg, bo,
                     wr_i, wr_f, wr_g, wr_o);
    if (t < 33) grid_barrier(bar, 256u * (unsigned)(t + 1));
  }
}

// ---------------------------------------------------------------------------
// head kernel: lx = x_emb @ W^T (no bias), ly = y_emb @ W^T + b, both heads.
// Output layout: [34][256][80] f32 each. Branchless split k-loops + unroll
// so loads pipeline across iterations.
// ---------------------------------------------------------------------------
__global__ __launch_bounds__(256) void head_kernel(
    const bf16* __restrict__ fwd_all, const bf16* __restrict__ rev_all,
    const bf16* __restrict__ y_all,
    const bf16* __restrict__ Wsub_b, const bf16* __restrict__ Wins_b,
    const float* __restrict__ b_sub, const float* __restrict__ b_ins,
    float* __restrict__ lx_sub, float* __restrict__ lx_ins,
    float* __restrict__ ly_sub, float* __restrict__ ly_ins) {
  const int lane = threadIdx.x & 63, wave = threadIdx.x >> 6;
  const int lo = lane & 15, quad = lane >> 4;
  int blk = blockIdx.x;
  bool yside = (blk >= 136);
  int mb = yside ? blk - 136 : blk;
  int mtile = mb * 4 + wave;   // 0..543
  int m0 = mtile * 16;
  int ij = m0 >> 8;            // i or j (m-tile never crosses an i boundary)
  int bb = m0 & 255;

  f32x4 acc[2][5];
#pragma unroll
  for (int h2 = 0; h2 < 2; ++h2)
#pragma unroll
    for (int n5 = 0; n5 < 5; ++n5) acc[h2][n5] = (f32x4){0.f, 0.f, 0.f, 0.f};

  const bf16* wrow[2][5];
#pragma unroll
  for (int n5 = 0; n5 < 5; ++n5) {
    wrow[0][n5] = Wsub_b + (size_t)(n5 * 16 + lo) * 1024 + quad * 8;
    wrow[1][n5] = Wins_b + (size_t)(n5 * 16 + lo) * 1024 + quad * 8;
  }

  if (!yside) {
    const bf16* Af = fwd_all + ((size_t)(ij + 1) * B_ + bb + lo) * 512 + quad * 8;
    const bf16* Ar = rev_all + ((size_t)(34 - ij) * B_ + bb + lo) * 512 + quad * 8;
#pragma unroll 4
    for (int kk = 0; kk < 512; kk += 32) {
      bf16x8 a = ldfrag(Af + kk);
#pragma unroll
      for (int h2 = 0; h2 < 2; ++h2)
#pragma unroll
        for (int n5 = 0; n5 < 5; ++n5)
          acc[h2][n5] = mfma16(a, ldfrag(wrow[h2][n5] + kk), acc[h2][n5]);
    }
#pragma unroll 4
    for (int kk = 0; kk < 512; kk += 32) {
      bf16x8 a = ldfrag(Ar + kk);
#pragma unroll
      for (int h2 = 0; h2 < 2; ++h2)
#pragma unroll
        for (int n5 = 0; n5 < 5; ++n5)
          acc[h2][n5] = mfma16(a, ldfrag(wrow[h2][n5] + 512 + kk), acc[h2][n5]);
    }
  } else {
    const bf16* Ay = y_all + ((size_t)(ij + 1) * B_ + bb + lo) * 1024 + quad * 8;
#pragma unroll 4
    for (int kk = 0; kk < 1024; kk += 32) {
      bf16x8 a = ldfrag(Ay + kk);
#pragma unroll
      for (int h2 = 0; h2 < 2; ++h2)
#pragma unroll
        for (int n5 = 0; n5 < 5; ++n5)
          acc[h2][n5] = mfma16(a, ldfrag(wrow[h2][n5] + kk), acc[h2][n5]);
    }
  }

#pragma unroll
  for (int h2 = 0; h2 < 2; ++h2) {
    float* dst = yside ? (h2 ? ly_ins : ly_sub) : (h2 ? lx_ins : lx_sub);
#pragma unroll
    for (int n5 = 0; n5 < 5; ++n5) {
      int n = n5 * 16 + lo;
      float bias = 0.0f;
      if (yside && n < 65) bias = h2 ? b_ins[n] : b_sub[n];
#pragma unroll
      for (int r = 0; r < 4; ++r) {
        int b = bb + quad * 4 + r;
        dst[((size_t)ij * B_ + b) * OP_ + n] = acc[h2][n5][r] + bias;
      }
    }
  }
}

// ---------------------------------------------------------------------------
// pair kernel: per (i,j,b): logsumexp over 65 of lx[i,b,:]+ly[j,b,:] for both
// heads; assemble the 4 output channels with masks. grid 34*34, block 256 (=b)
// ---------------------------------------------------------------------------
__device__ __forceinline__ void head_lse(const float* __restrict__ px,
                                         const float* __restrict__ py, int sym,
                                         float& logZ, float& v64, float& vs) {
  float v[68];
  const float4* px4 = reinterpret_cast<const float4*>(px);
  const float4* py4 = reinterpret_cast<const float4*>(py);
#pragma unroll
  for (int q = 0; q < 17; ++q) {
    float4 xa = px4[q], yb = py4[q];
    v[4 * q + 0] = xa.x + yb.x;
    v[4 * q + 1] = xa.y + yb.y;
    v[4 * q + 2] = xa.z + yb.z;
    v[4 * q + 3] = xa.w + yb.w;
  }
  float m = v[0];
#pragma unroll
  for (int o = 1; o < 65; ++o) m = fmaxf(m, v[o]);
  float s = 0.0f;
  float vsl = 0.0f;
#pragma unroll
  for (int o = 0; o < 65; ++o) {
    s += __expf(v[o] - m);
    if (o < 64) vsl = (o == sym) ? v[o] : vsl;
  }
  logZ = m + __logf(s);
  v64 = v[64];
  vs = vsl;
}

__global__ __launch_bounds__(256) void pair_kernel(
    const int* __restrict__ tok_x, const int* __restrict__ tok_y,
    const float* __restrict__ lx_sub, const float* __restrict__ lx_ins,
    const float* __restrict__ ly_sub, const float* __restrict__ ly_ins,
    float* __restrict__ out) {
  const int i = blockIdx.x / SY_;
  const int j = blockIdx.x % SY_;
  const int b = threadIdx.x;
  const size_t CH = (size_t)SX_ * SY_ * B_;
  size_t obase = ((size_t)i * SY_ + j) * B_ + b;

  if (j == SY_ - 1) {  // j_ok false for every b
    out[obase] = BIG_NEG;
    out[CH + obase] = BIG_NEG;
    out[2 * CH + obase] = BIG_NEG;
    out[3 * CH + obase] = BIG_NEG;
    return;
  }

  int tx = tok_x[i * B_ + b];
  int ty = tok_y[j * B_ + b];
  bool valid = (tx >= 0) && (ty >= 0);
  if (!valid) {
    out[obase] = BIG_NEG;
    out[CH + obase] = BIG_NEG;
    out[2 * CH + obase] = BIG_NEG;
    out[3 * CH + obase] = BIG_NEG;
    return;
  }

  int tn = tok_y[(j + 1) * B_ + b];
  bool ins_ok = (tn != 65);
  int sym = (tn >= 0 && tn < 64) ? tn : -1;

  const float* pxs = lx_sub + ((size_t)i * B_ + b) * OP_;
  const float* pys = ly_sub + ((size_t)j * B_ + b) * OP_;
  const float* pxi = lx_ins + ((size_t)i * B_ + b) * OP_;
  const float* pyi = ly_ins + ((size_t)j * B_ + b) * OP_;

  float logZs, v64s, vss;
  head_lse(pxs, pys, sym, logZs, v64s, vss);
  float dlt = v64s - logZs;
  float sub_val = (sym >= 0) ? (vss - logZs) : 0.0f;

  float logZi, v64i, vsi;
  head_lse(pxi, pyi, sym, logZi, v64i, vsi);
  float endv = v64i - logZi;
  float ins_val = (sym >= 0) ? (vsi - logZi) : 0.0f;

  out[obase]          = ins_ok ? ins_val : BIG_NEG;  // ch0: ins
  out[CH + obase]     = ins_ok ? sub_val : BIG_NEG;  // ch1: sub
  out[2 * CH + obase] = endv;                        // ch2: end (valid here)
  out[3 * CH + obase] = dlt;                         // ch3: del
}

// ---------------------------------------------------------------------------
// launch
// ---------------------------------------------------------------------------
extern "C" void kernel_launch(void* const* d_in, const int* in_sizes, int n_in,
                              void* d_out, int out_size, void* d_ws, size_t ws_size,
                              hipStream_t stream) {
  const float* sources = (const float*)d_in[0];
  const float* targets = (const float*)d_in[1];
  const float* Wih_f = (const float*)d_in[2];
  const float* Whh_f = (const float*)d_in[3];
  const float* b_f   = (const float*)d_in[4];
  const float* Wih_r = (const float*)d_in[5];
  const float* Whh_r = (const float*)d_in[6];
  const float* b_r   = (const float*)d_in[7];
  const float* Wih_m = (const float*)d_in[8];
  const float* Whh_m = (const float*)d_in[9];
  const float* b_m   = (const float*)d_in[10];
  const float* W_sub = (const float*)d_in[11];
  const float* b_sub = (const float*)d_in[12];
  const float* W_ins = (const float*)d_in[13];
  const float* b_ins = (const float*)d_in[14];
  float* out = (float*)d_out;

  // workspace layout
  char* w = (char*)d_ws;
  constexpr size_t BAR_SZ  = 256;
  constexpr size_t TOK_SZ  = (size_t)SX_ * B_ * 4;              // 34816
  constexpr size_t WPAD_SZ = (size_t)OP_ * 1024 * 2;            // 160 KiB
  constexpr size_t LX_SZ   = (size_t)SX_ * B_ * OP_ * 4;        // ~2.79 MiB
  constexpr size_t HF_SZ   = (size_t)35 * B_ * 512 * 2;         // 8.96 MiB
  constexpr size_t HM_SZ   = (size_t)35 * B_ * 1024 * 2;        // 17.9 MiB

  size_t off = 0;
  unsigned* bar = (unsigned*)(w + off); off += BAR_SZ;
  int*  tok_x   = (int*)(w + off);  off += TOK_SZ;
  int*  tok_y   = (int*)(w + off);  off += TOK_SZ;
  off = (off + 255) & ~(size_t)255;
  bf16* Wsub_b  = (bf16*)(w + off); off += WPAD_SZ;
  bf16* Wins_b  = (bf16*)(w + off); off += WPAD_SZ;
  float* lx_sub = (float*)(w + off); off += LX_SZ;
  float* lx_ins = (float*)(w + off); off += LX_SZ;
  float* ly_sub = (float*)(w + off); off += LX_SZ;
  float* ly_ins = (float*)(w + off); off += LX_SZ;
  bf16* fwd_all = (bf16*)(w + off); off += HF_SZ;
  bf16* rev_all = (bf16*)(w + off); off += HF_SZ;
  bf16* y_all   = (bf16*)(w + off); off += HM_SZ;
  (void)ws_size; (void)in_sizes; (void)n_in; (void)out_size;

  // zero: barrier counter + the three h[0] slabs (c-state lives in registers)
  hipMemsetAsync(bar, 0, BAR_SZ, stream);
  hipMemsetAsync(fwd_all, 0, (size_t)B_ * 512 * 2, stream);
  hipMemsetAsync(rev_all, 0, (size_t)B_ * 512 * 2, stream);
  hipMemsetAsync(y_all,   0, (size_t)B_ * 1024 * 2, stream);

  decode_tokens<<<(2 * SX_ * B_ + 255) / 256, 256, 0, stream>>>(sources, targets, tok_x, tok_y);
  pad_head_w<<<(OP_ * 1024 + 255) / 256, 256, 0, stream>>>(W_sub, W_ins, Wsub_b, Wins_b);

  lstm_persist<<<256, 256, 0, stream>>>(
      tok_x, tok_y,
      Wih_f, b_f, Whh_f,
      Wih_r, b_r, Whh_r,
      Wih_m, b_m, Whh_m,
      fwd_all, rev_all, y_all, bar);

  head_kernel<<<272, 256, 0, stream>>>(fwd_all, rev_all, y_all, Wsub_b, Wins_b,
                                       b_sub, b_ins, lx_sub, lx_ins, ly_sub, ly_ins);

  pair_kernel<<<SX_ * SY_, 256, 0, stream>>>(tok_x, tok_y, lx_sub, lx_ins,
                                             ly_sub, ly_ins, out);
}